// Round 4
// baseline (193.409 us; speedup 1.0000x reference)
//
#include <hip/hip_runtime.h>
#include <math.h>

#define BB 32
#define WW 100
#define FF 128
#define KS 7
#define ET 256   // 2F (temporal GAT embed)
#define EF 200   // 2W (feature GAT embed)

// ---------------- workspace layout (floats) ----------------
// x1:   0        409600   pos-encoded input (B,W,F)
// x2:   409600   409600   conv output (B,W,F)
// x3T:  819200   409600   temporal GAT output, TRANSPOSED (B,F,W)
// LT:   1228800  819200   temporal left TRANSPOSED (B,256,100) -> reused LfT (B,200,128)
// Rt:   2048000  819200   temporal right TRANSPOSED (B,256,100) -> reused RfT (B,200,128)
// tj:   2867200  4096     tj[b][j] = sum_w fcw[w]*x4[b,w,j]
// wt:   3297280  114688   conv weights transposed (I,K,O)
// tlwT: 3411968  65536    temp_lin_w transposed (256,256)
// flwT: 3477504  40000    feat_lin_w transposed (200,200)

// K0: x1 = x + pos-encode; transpose the three weight tensors
__global__ void k_prep(const float* __restrict__ x, const float* __restrict__ cw,
                       const float* __restrict__ tlw, const float* __restrict__ flw,
                       float* __restrict__ x1, float* __restrict__ wt,
                       float* __restrict__ tlwT, float* __restrict__ flwT) {
    int id = blockIdx.x * 256 + threadIdx.x;
    if (id < BB * WW * FF) {
        int f = id & (FF - 1);
        int w = (id >> 7) % WW;
        float div = __expf((float)f * (-9.210340371976184f / (float)FF));
        float arg = (float)w * div;
        x1[id] = x[id] + __sinf(arg) + __cosf(arg);
    }
    if (id < KS * FF * FF) {
        // wt[i][k][o] = cw[o][i][k]
        int o = id & (FF - 1);
        int r = id >> 7;
        int k = r % KS;
        int i = r / KS;
        wt[id] = cw[(o * FF + i) * KS + k];
    }
    if (id < ET * ET) {
        int e = id & (ET - 1);
        int d = id >> 8;
        tlwT[id] = tlw[e * ET + d];
    }
    if (id < EF * EF) {
        int e = id % EF;
        int d = id / EF;
        flwT[id] = flw[e * EF + d];
    }
}

// K1: Conv1d 'same' + relu. 512 thr = o(128) x h(4); h splits INPUT channels
// (32 i each) -> zero weight-fetch redundancy; partials reduced via LDS.
// x1 read with wave-uniform addresses (scalar path), no staging LDS.
#define CTW 12
#define NTILE 9
__global__ __launch_bounds__(512) void k_conv(const float* __restrict__ x1,
                                              const float* __restrict__ wt,
                                              const float* __restrict__ cb,
                                              float* __restrict__ x2) {
    int tile = blockIdx.x % NTILE;
    int b = blockIdx.x / NTILE;
    int w0 = tile * CTW;
    int o = threadIdx.x & (FF - 1);
    int h = threadIdx.x >> 7;   // i-quarter, wave-uniform
    float acc[CTW];
#pragma unroll
    for (int t = 0; t < CTW; ++t) acc[t] = 0.f;
    const float* xb = x1 + b * WW * FF;
    for (int p = 0; p < 16; ++p) {
        int i = h * 32 + p * 2;
        float xa[CTW + KS - 1], xc[CTW + KS - 1];
#pragma unroll
        for (int r = 0; r < CTW + KS - 1; ++r) {
            int t = w0 - 3 + r;
            if ((unsigned)t < WW) {
                float2 v = *(const float2*)&xb[t * FF + i];
                xa[r] = v.x; xc[r] = v.y;
            } else { xa[r] = 0.f; xc[r] = 0.f; }
        }
#pragma unroll
        for (int k = 0; k < KS; ++k) {
            float wa = wt[(i * KS + k) * FF + o];
            float wc = wt[((i + 1) * KS + k) * FF + o];
#pragma unroll
            for (int t = 0; t < CTW; ++t)
                acc[t] += xa[t + k] * wa + xc[t + k] * wc;
        }
    }
    __shared__ float part[4][CTW][FF];
#pragma unroll
    for (int t = 0; t < CTW; ++t) part[h][t][o] = acc[t];
    __syncthreads();
    for (int c = threadIdx.x; c < CTW * FF; c += 512) {
        int t = c >> 7, oo = c & (FF - 1);
        float s = part[0][t][oo] + part[1][t][oo] + part[2][t][oo] +
                  part[3][t][oo] + cb[oo];
        int w = w0 + t;
        if (w < WW) x2[(b * WW + w) * FF + oo] = fmaxf(s, 0.f);
    }
}

// K2: temporal L/R GEMM, 8 rows/block. Both outputs TRANSPOSED: LT/Rt (B,256,100).
__global__ __launch_bounds__(256) void k_lr_t(const float* __restrict__ x2,
                                              const float* __restrict__ tlwT,
                                              const float* __restrict__ tlb,
                                              float* __restrict__ LT,
                                              float* __restrict__ Rt) {
    int tile = blockIdx.x % 13;
    int b = blockIdx.x / 13;
    int i0 = tile * 8;
    int e = threadIdx.x;
    int nv = WW - i0; if (nv > 8) nv = 8;   // 8, or 4 on last tile
    const float* xrow = x2 + (b * WW + i0) * FF;
    float aL[8] = {0,0,0,0,0,0,0,0}, aR[8] = {0,0,0,0,0,0,0,0};
    for (int dc = 0; dc < 32; ++dc) {
        float xs_[8][4];
#pragma unroll
        for (int r = 0; r < 8; ++r)
            *(float4*)xs_[r] = *(const float4*)&xrow[r * FF + dc * 4];  // uniform
#pragma unroll
        for (int q = 0; q < 4; ++q) {
            int d = dc * 4 + q;
            float wL = tlwT[d * ET + e];
            float wR = tlwT[(FF + d) * ET + e];
#pragma unroll
            for (int r = 0; r < 8; ++r) {
                aL[r] += xs_[r][q] * wL;
                aR[r] += xs_[r][q] * wR;
            }
        }
    }
    float lb = tlb[e];
    float o0[8];
#pragma unroll
    for (int r = 0; r < 8; ++r) o0[r] = aL[r] + lb;
    float* Lp = LT + (b * ET + e) * WW + i0;
    float* Rp = Rt + (b * ET + e) * WW + i0;
    *(float4*)Lp = *(float4*)&o0[0];
    *(float4*)Rp = *(float4*)&aR[0];
    if (nv == 8) {
        *(float4*)(Lp + 4) = *(float4*)&o0[4];
        *(float4*)(Rp + 4) = *(float4*)&aR[4];
    }
}

// K3: temporal attention, QT=8 queries/block. threads = j(128) x q(2).
__global__ __launch_bounds__(256) void k_att_t(const float* __restrict__ LT,
                                               const float* __restrict__ Rt,
                                               const float* __restrict__ ta,
                                               const float* __restrict__ tbias,
                                               const float* __restrict__ x2,
                                               float* __restrict__ x3T) {
    int tile = blockIdx.x % 13;
    int b = blockIdx.x / 13;
    int i0 = tile * 8;
    int tid = threadIdx.x;
    int j = tid & 127, q = tid >> 7;
    const float* Lb = LT + (b * ET) * WW + i0 + q * 4;   // uniform per wave
    const float* Rb = Rt + (b * ET) * WW;
    float s0 = 0.f, s1 = 0.f, s2 = 0.f, s3 = 0.f;
    for (int e = 0; e < ET; ++e) {
        float rj = Rb[e * WW + j];
        float4 lv = *(const float4*)&Lb[e * WW];
        float ae = ta[e];
        float v;
        v = lv.x + rj; v = fmaxf(v, 0.2f * v); s0 += v * ae;
        v = lv.y + rj; v = fmaxf(v, 0.2f * v); s1 += v * ae;
        v = lv.z + rj; v = fmaxf(v, 0.2f * v); s2 += v * ae;
        v = lv.w + rj; v = fmaxf(v, 0.2f * v); s3 += v * ae;
    }
    float ej[4] = {s0, s1, s2, s3};
#pragma unroll
    for (int ii = 0; ii < 4; ++ii) {
        int i = i0 + q * 4 + ii;
        float bsv = (j < WW && i < WW) ? tbias[i * WW + j] : 0.f;
        ej[ii] = (j < WW) ? ej[ii] + bsv : -1e30f;
    }
    __shared__ float redA[4][4], redB[4][4];
    float m[4] = {ej[0], ej[1], ej[2], ej[3]};
#pragma unroll
    for (int off = 32; off > 0; off >>= 1) {
#pragma unroll
        for (int ii = 0; ii < 4; ++ii) m[ii] = fmaxf(m[ii], __shfl_xor(m[ii], off));
    }
    int wv = tid >> 6;
    if ((tid & 63) == 0) {
#pragma unroll
        for (int ii = 0; ii < 4; ++ii) redA[wv][ii] = m[ii];
    }
    __syncthreads();
    float p[4], ps[4];
#pragma unroll
    for (int ii = 0; ii < 4; ++ii) {
        float mx = fmaxf(redA[wv][ii], redA[wv ^ 1][ii]);
        p[ii] = (j < WW) ? __expf(ej[ii] - mx) : 0.f;
        ps[ii] = p[ii];
    }
#pragma unroll
    for (int off = 32; off > 0; off >>= 1) {
#pragma unroll
        for (int ii = 0; ii < 4; ++ii) ps[ii] += __shfl_xor(ps[ii], off);
    }
    if ((tid & 63) == 0) {
#pragma unroll
        for (int ii = 0; ii < 4; ++ii) redB[wv][ii] = ps[ii];
    }
    __syncthreads();
    __shared__ float attT[WW][12];
    if (j < WW) {
#pragma unroll
        for (int ii = 0; ii < 4; ++ii) {
            float inv = 1.f / (redB[wv][ii] + redB[wv ^ 1][ii]);
            attT[j][q * 4 + ii] = p[ii] * inv;
        }
    }
    __syncthreads();
    // PV: threads = d(128) x ph(2); ph*4+ii indexes the 8 queries
    int d = tid & 127, ph = tid >> 7;
    float pv0 = 0.f, pv1 = 0.f, pv2 = 0.f, pv3 = 0.f;
    for (int jj = 0; jj < WW; ++jj) {
        float4 av = *(const float4*)&attT[jj][ph * 4];
        float xv = x2[(b * WW + jj) * FF + d];
        pv0 += av.x * xv; pv1 += av.y * xv; pv2 += av.z * xv; pv3 += av.w * xv;
    }
    __shared__ float ob[FF][12];
    ob[d][ph * 4 + 0] = tanhf(pv0);
    ob[d][ph * 4 + 1] = tanhf(pv1);
    ob[d][ph * 4 + 2] = tanhf(pv2);
    ob[d][ph * 4 + 3] = tanhf(pv3);
    __syncthreads();
    {
        int f = tid >> 1, h4 = (tid & 1) * 4;
        if (i0 + h4 < WW) {
            float4 v = *(const float4*)&ob[f][h4];
            *(float4*)&x3T[(b * FF + f) * WW + i0 + h4] = v;
        }
    }
}

// K4: feature L/R GEMM, 8 f-rows/block. LfT/RfT (B,200,128) transposed.
__global__ __launch_bounds__(256) void k_lr_f(const float* __restrict__ x3T,
                                              const float* __restrict__ flwT,
                                              const float* __restrict__ flb,
                                              float* __restrict__ LfT,
                                              float* __restrict__ RfT) {
    int tile = blockIdx.x & 15;
    int b = blockIdx.x >> 4;
    int f0 = tile * 8;
    int e = threadIdx.x;
    if (e >= EF) return;
    const float* xrow = x3T + (b * FF + f0) * WW;
    float aL[8] = {0,0,0,0,0,0,0,0}, aR[8] = {0,0,0,0,0,0,0,0};
    for (int dc = 0; dc < 25; ++dc) {
        float xs_[8][4];
#pragma unroll
        for (int r = 0; r < 8; ++r)
            *(float4*)xs_[r] = *(const float4*)&xrow[r * WW + dc * 4];  // uniform
#pragma unroll
        for (int q = 0; q < 4; ++q) {
            int d = dc * 4 + q;
            float wL = flwT[d * EF + e];
            float wR = flwT[(WW + d) * EF + e];
#pragma unroll
            for (int r = 0; r < 8; ++r) {
                aL[r] += xs_[r][q] * wL;
                aR[r] += xs_[r][q] * wR;
            }
        }
    }
    float lb = flb[e];
    float o0[8];
#pragma unroll
    for (int r = 0; r < 8; ++r) o0[r] = aL[r] + lb;
    float* Lp = LfT + (b * EF + e) * FF + f0;
    float* Rp = RfT + (b * EF + e) * FF + f0;
    *(float4*)Lp = *(float4*)&o0[0];
    *(float4*)(Lp + 4) = *(float4*)&o0[4];
    *(float4*)Rp = *(float4*)&aR[0];
    *(float4*)(Rp + 4) = *(float4*)&aR[4];
}

// K5: feature attention, QT=8 + fused tj reduction (x4 never materialized).
__global__ __launch_bounds__(256) void k_att_f(const float* __restrict__ LfT,
                                               const float* __restrict__ RfT,
                                               const float* __restrict__ fa,
                                               const float* __restrict__ fbias,
                                               const float* __restrict__ x3T,
                                               const float* __restrict__ fcw,
                                               float* __restrict__ tj) {
    int tile = blockIdx.x & 15;
    int b = blockIdx.x >> 4;
    int f0 = tile * 8;
    int tid = threadIdx.x;
    int j = tid & 127, q = tid >> 7;
    const float* Lb = LfT + (b * EF) * FF + f0 + q * 4;
    const float* Rb = RfT + (b * EF) * FF;
    float s0 = 0.f, s1 = 0.f, s2 = 0.f, s3 = 0.f;
    for (int e = 0; e < EF; ++e) {
        float rj = Rb[e * FF + j];
        float4 lv = *(const float4*)&Lb[e * FF];
        float ae = fa[e];
        float v;
        v = lv.x + rj; v = fmaxf(v, 0.2f * v); s0 += v * ae;
        v = lv.y + rj; v = fmaxf(v, 0.2f * v); s1 += v * ae;
        v = lv.z + rj; v = fmaxf(v, 0.2f * v); s2 += v * ae;
        v = lv.w + rj; v = fmaxf(v, 0.2f * v); s3 += v * ae;
    }
    float ej[4] = {s0, s1, s2, s3};
#pragma unroll
    for (int ii = 0; ii < 4; ++ii)
        ej[ii] += fbias[(f0 + q * 4 + ii) * FF + j];
    __shared__ float redA[4][4], redB[4][4];
    float m[4] = {ej[0], ej[1], ej[2], ej[3]};
#pragma unroll
    for (int off = 32; off > 0; off >>= 1) {
#pragma unroll
        for (int ii = 0; ii < 4; ++ii) m[ii] = fmaxf(m[ii], __shfl_xor(m[ii], off));
    }
    int wv = tid >> 6;
    if ((tid & 63) == 0) {
#pragma unroll
        for (int ii = 0; ii < 4; ++ii) redA[wv][ii] = m[ii];
    }
    __syncthreads();
    float p[4], ps[4];
#pragma unroll
    for (int ii = 0; ii < 4; ++ii) {
        float mx = fmaxf(redA[wv][ii], redA[wv ^ 1][ii]);
        p[ii] = __expf(ej[ii] - mx);
        ps[ii] = p[ii];
    }
#pragma unroll
    for (int off = 32; off > 0; off >>= 1) {
#pragma unroll
        for (int ii = 0; ii < 4; ++ii) ps[ii] += __shfl_xor(ps[ii], off);
    }
    if ((tid & 63) == 0) {
#pragma unroll
        for (int ii = 0; ii < 4; ++ii) redB[wv][ii] = ps[ii];
    }
    __syncthreads();
    __shared__ float attT[FF][12];
#pragma unroll
    for (int ii = 0; ii < 4; ++ii) {
        float inv = 1.f / (redB[wv][ii] + redB[wv ^ 1][ii]);
        attT[j][q * 4 + ii] = p[ii] * inv;
    }
    __syncthreads();
    // PV + tanh + fcw-weighted reduce over w
    int w = tid & 127, ph = tid >> 7;
    float pv[4] = {0.f, 0.f, 0.f, 0.f};
    float fcv = (w < WW) ? fcw[w] : 0.f;
    bool wok = (w < WW);
    for (int jj = 0; jj < FF; ++jj) {
        float4 av = *(const float4*)&attT[jj][ph * 4];
        float xv = wok ? x3T[(b * FF + jj) * WW + w] : 0.f;
        pv[0] += av.x * xv; pv[1] += av.y * xv;
        pv[2] += av.z * xv; pv[3] += av.w * xv;
    }
    float tv[4];
#pragma unroll
    for (int ii = 0; ii < 4; ++ii) tv[ii] = tanhf(pv[ii]) * fcv;
#pragma unroll
    for (int off = 32; off > 0; off >>= 1) {
#pragma unroll
        for (int ii = 0; ii < 4; ++ii) tv[ii] += __shfl_xor(tv[ii], off);
    }
    __shared__ float redT[4][4];
    if ((tid & 63) == 0) {
#pragma unroll
        for (int ii = 0; ii < 4; ++ii) redT[tid >> 6][ii] = tv[ii];
    }
    __syncthreads();
    if (tid < 8) {
        int hh = tid >> 2, ii = tid & 3;
        tj[b * FF + f0 + hh * 4 + ii] = redT[hh * 2][ii] + redT[hh * 2 + 1][ii];
    }
}

// K6: out[b,f] = tanh(sum_j cos(f,j)*tj[b,j] + fcb). cos from normalized emb.
__global__ __launch_bounds__(128) void k_fc(const float* __restrict__ tjg,
                                            const float* __restrict__ emb,
                                            const float* __restrict__ fcb,
                                            float* __restrict__ out) {
    int b = blockIdx.x;
    int f = threadIdx.x;
    __shared__ float en[FF][12];
    __shared__ float tjs[FF];
    {
        float4 e0 = *(const float4*)&emb[f * 8];
        float4 e1 = *(const float4*)&emb[f * 8 + 4];
        float n = e0.x*e0.x + e0.y*e0.y + e0.z*e0.z + e0.w*e0.w +
                  e1.x*e1.x + e1.y*e1.y + e1.z*e1.z + e1.w*e1.w;
        float rin = rsqrtf(n);
        float4 a = make_float4(e0.x*rin, e0.y*rin, e0.z*rin, e0.w*rin);
        float4 c = make_float4(e1.x*rin, e1.y*rin, e1.z*rin, e1.w*rin);
        *(float4*)&en[f][0] = a;
        *(float4*)&en[f][4] = c;
        tjs[f] = tjg[b * FF + f];
    }
    __syncthreads();
    float er[8];
#pragma unroll
    for (int k = 0; k < 8; ++k) er[k] = en[f][k];
    float acc = fcb[0];
    for (int jj = 0; jj < FF; ++jj) {
        float4 a = *(const float4*)&en[jj][0];
        float4 c = *(const float4*)&en[jj][4];
        float d8 = er[0]*a.x + er[1]*a.y + er[2]*a.z + er[3]*a.w +
                   er[4]*c.x + er[5]*c.y + er[6]*c.z + er[7]*c.w;
        acc += d8 * tjs[jj];
    }
    out[b * FF + f] = tanhf(acc);
}

extern "C" void kernel_launch(void* const* d_in, const int* in_sizes, int n_in,
                              void* d_out, int out_size, void* d_ws, size_t ws_size,
                              hipStream_t stream) {
    const float* x     = (const float*)d_in[0];
    const float* cw    = (const float*)d_in[1];
    const float* cb    = (const float*)d_in[2];
    const float* tlw   = (const float*)d_in[3];
    const float* tlb   = (const float*)d_in[4];
    const float* ta    = (const float*)d_in[5];
    const float* tbias = (const float*)d_in[6];
    const float* flw   = (const float*)d_in[7];
    const float* flb   = (const float*)d_in[8];
    const float* fa    = (const float*)d_in[9];
    const float* fbias = (const float*)d_in[10];
    const float* emb   = (const float*)d_in[11];
    const float* fcw   = (const float*)d_in[12];
    const float* fcb   = (const float*)d_in[13];
    float* out = (float*)d_out;
    float* ws = (float*)d_ws;

    float* x1   = ws + 0;
    float* x2   = ws + 409600;
    float* x3T  = ws + 819200;
    float* LT   = ws + 1228800;   // reused as LfT
    float* Rt   = ws + 2048000;   // reused as RfT
    float* tj   = ws + 2867200;
    float* wt   = ws + 3297280;
    float* tlwT = ws + 3411968;
    float* flwT = ws + 3477504;

    k_prep<<<1600, 256, 0, stream>>>(x, cw, tlw, flw, x1, wt, tlwT, flwT);
    k_conv<<<BB * NTILE, 512, 0, stream>>>(x1, wt, cb, x2);
    k_lr_t<<<BB * 13, 256, 0, stream>>>(x2, tlwT, tlb, LT, Rt);
    k_att_t<<<BB * 13, 256, 0, stream>>>(LT, Rt, ta, tbias, x2, x3T);
    k_lr_f<<<BB * 16, 256, 0, stream>>>(x3T, flwT, flb, LT, Rt);
    k_att_f<<<BB * 16, 256, 0, stream>>>(LT, Rt, fa, fbias, x3T, fcw, tj);
    k_fc<<<BB, 128, 0, stream>>>(tj, emb, fcb, out);
}

// Round 5
// 152.395 us; speedup vs baseline: 1.2691x; 1.2691x over previous
//
#include <hip/hip_runtime.h>
#include <math.h>

#define BB 32
#define WW 100
#define FF 128
#define KS 7
#define ET 256   // 2F (temporal GAT embed)
#define EF 200   // 2W (feature GAT embed)

// ---------------- workspace layout (floats) ----------------
// x1:   0        409600   pos-encoded input (B,W,F)
// x2:   409600   409600   conv output (B,W,F)
// x3T:  819200   409600   temporal GAT output, TRANSPOSED (B,F,W)
// LT:   1228800  819200   temporal left TRANSPOSED (B,256,100) -> reused LfT (B,200,128)
// Rt:   2048000  819200   temporal right TRANSPOSED (B,256,100) -> reused RfT (B,200,128)
// tj:   2867200  4096     tj[b][j] = sum_w fcw[w]*x4[b,w,j]
// wt:   3297280  114688   conv weights transposed (I,K,O)
// tlwT: 3411968  65536    temp_lin_w transposed (256,256)
// flwT: 3477504  40000    feat_lin_w transposed (200,200)

// K0: x1 = x + pos-encode; transpose the three weight tensors
__global__ void k_prep(const float* __restrict__ x, const float* __restrict__ cw,
                       const float* __restrict__ tlw, const float* __restrict__ flw,
                       float* __restrict__ x1, float* __restrict__ wt,
                       float* __restrict__ tlwT, float* __restrict__ flwT) {
    int id = blockIdx.x * 256 + threadIdx.x;
    if (id < BB * WW * FF) {
        int f = id & (FF - 1);
        int w = (id >> 7) % WW;
        float div = __expf((float)f * (-9.210340371976184f / (float)FF));
        float arg = (float)w * div;
        x1[id] = x[id] + __sinf(arg) + __cosf(arg);
    }
    if (id < KS * FF * FF) {
        // wt[i][k][o] = cw[o][i][k]
        int o = id & (FF - 1);
        int r = id >> 7;
        int k = r % KS;
        int i = r / KS;
        wt[id] = cw[(o * FF + i) * KS + k];
    }
    if (id < ET * ET) {
        int e = id & (ET - 1);
        int d = id >> 8;
        tlwT[id] = tlw[e * ET + d];
    }
    if (id < EF * EF) {
        int e = id % EF;
        int d = id / EF;
        flwT[id] = flw[e * EF + d];
    }
}

// K1: Conv1d 'same' + relu. TW=10 (10 tiles, no edge guards).
// 256 thr = (o:128) x (i-half:2). LDS x-tile TRANSPOSED xs[f][r]:
// staging is f-coalesced; compute reads are same-address broadcasts.
// Per thread per i: 4 ds_read_b128 + 7 coalesced weight loads + 70 FMA.
#define CTW 10
#define NTILE 10
#define NROW 16            // CTW + KS - 1
#define XPAD 20            // row stride (floats): 16B-aligned rows
__global__ __launch_bounds__(256) void k_conv(const float* __restrict__ x1,
                                              const float* __restrict__ wt,
                                              const float* __restrict__ cb,
                                              float* __restrict__ x2) {
    int tile = blockIdx.x % NTILE;
    int b = blockIdx.x / NTILE;
    int w0 = tile * CTW;
    int tid = threadIdx.x;
    int o = tid & (FF - 1);
    int h = tid >> 7;   // i-half, wave-uniform
    __shared__ float xs[FF][XPAD];
    __shared__ float part0[CTW][FF];
    __shared__ float part1[CTW][FF];
    // stage: 16 rows x 128 f, coalesced over f, transposed into xs[f][r]
    for (int idx = tid; idx < NROW * FF; idx += 256) {
        int r = idx >> 7, f = idx & (FF - 1);
        int t = w0 - 3 + r;
        xs[f][r] = ((unsigned)t < WW) ? x1[(b * WW + t) * FF + f] : 0.f;
    }
    __syncthreads();
    float acc[CTW];
#pragma unroll
    for (int t = 0; t < CTW; ++t) acc[t] = 0.f;
    const float* wbase = wt + (h * 64) * KS * FF + o;
#pragma unroll 2
    for (int il = 0; il < 64; ++il) {
        int i = h * 64 + il;
        float4 X0 = *(const float4*)&xs[i][0];
        float4 X1 = *(const float4*)&xs[i][4];
        float4 X2 = *(const float4*)&xs[i][8];
        float4 X3 = *(const float4*)&xs[i][12];
        float xr[16] = {X0.x, X0.y, X0.z, X0.w, X1.x, X1.y, X1.z, X1.w,
                        X2.x, X2.y, X2.z, X2.w, X3.x, X3.y, X3.z, X3.w};
        const float* wp = wbase + il * KS * FF;
#pragma unroll
        for (int k = 0; k < KS; ++k) {
            float wv = wp[k * FF];
#pragma unroll
            for (int t = 0; t < CTW; ++t) acc[t] += xr[t + k] * wv;
        }
    }
    float* pp = h ? &part1[0][0] : &part0[0][0];
#pragma unroll
    for (int t = 0; t < CTW; ++t) pp[t * FF + o] = acc[t];
    __syncthreads();
    for (int idx = tid; idx < CTW * FF; idx += 256) {
        int t = idx >> 7, oo = idx & (FF - 1);
        float s = part0[t][oo] + part1[t][oo] + cb[oo];
        x2[(b * WW + w0 + t) * FF + oo] = fmaxf(s, 0.f);
    }
}

// K2: temporal L/R GEMM, 8 rows/block. Both outputs TRANSPOSED: LT/Rt (B,256,100).
__global__ __launch_bounds__(256) void k_lr_t(const float* __restrict__ x2,
                                              const float* __restrict__ tlwT,
                                              const float* __restrict__ tlb,
                                              float* __restrict__ LT,
                                              float* __restrict__ Rt) {
    int tile = blockIdx.x % 13;
    int b = blockIdx.x / 13;
    int i0 = tile * 8;
    int e = threadIdx.x;
    int nv = WW - i0; if (nv > 8) nv = 8;   // 8, or 4 on last tile
    const float* xrow = x2 + (b * WW + i0) * FF;
    float aL[8] = {0,0,0,0,0,0,0,0}, aR[8] = {0,0,0,0,0,0,0,0};
    for (int dc = 0; dc < 32; ++dc) {
        float xs_[8][4];
#pragma unroll
        for (int r = 0; r < 8; ++r)
            *(float4*)xs_[r] = *(const float4*)&xrow[r * FF + dc * 4];  // uniform
#pragma unroll
        for (int q = 0; q < 4; ++q) {
            int d = dc * 4 + q;
            float wL = tlwT[d * ET + e];
            float wR = tlwT[(FF + d) * ET + e];
#pragma unroll
            for (int r = 0; r < 8; ++r) {
                aL[r] += xs_[r][q] * wL;
                aR[r] += xs_[r][q] * wR;
            }
        }
    }
    float lb = tlb[e];
    float o0[8];
#pragma unroll
    for (int r = 0; r < 8; ++r) o0[r] = aL[r] + lb;
    float* Lp = LT + (b * ET + e) * WW + i0;
    float* Rp = Rt + (b * ET + e) * WW + i0;
    *(float4*)Lp = *(float4*)&o0[0];
    *(float4*)Rp = *(float4*)&aR[0];
    if (nv == 8) {
        *(float4*)(Lp + 4) = *(float4*)&o0[4];
        *(float4*)(Rp + 4) = *(float4*)&aR[4];
    }
}

// K3: temporal attention, QT=8 queries/block. threads = j(128) x q(2).
__global__ __launch_bounds__(256) void k_att_t(const float* __restrict__ LT,
                                               const float* __restrict__ Rt,
                                               const float* __restrict__ ta,
                                               const float* __restrict__ tbias,
                                               const float* __restrict__ x2,
                                               float* __restrict__ x3T) {
    int tile = blockIdx.x % 13;
    int b = blockIdx.x / 13;
    int i0 = tile * 8;
    int tid = threadIdx.x;
    int j = tid & 127, q = tid >> 7;
    const float* Lb = LT + (b * ET) * WW + i0 + q * 4;   // uniform per wave
    const float* Rb = Rt + (b * ET) * WW;
    float s0 = 0.f, s1 = 0.f, s2 = 0.f, s3 = 0.f;
    for (int e = 0; e < ET; ++e) {
        float rj = Rb[e * WW + j];
        float4 lv = *(const float4*)&Lb[e * WW];
        float ae = ta[e];
        float v;
        v = lv.x + rj; v = fmaxf(v, 0.2f * v); s0 += v * ae;
        v = lv.y + rj; v = fmaxf(v, 0.2f * v); s1 += v * ae;
        v = lv.z + rj; v = fmaxf(v, 0.2f * v); s2 += v * ae;
        v = lv.w + rj; v = fmaxf(v, 0.2f * v); s3 += v * ae;
    }
    float ej[4] = {s0, s1, s2, s3};
#pragma unroll
    for (int ii = 0; ii < 4; ++ii) {
        int i = i0 + q * 4 + ii;
        float bsv = (j < WW && i < WW) ? tbias[i * WW + j] : 0.f;
        ej[ii] = (j < WW) ? ej[ii] + bsv : -1e30f;
    }
    __shared__ float redA[4][4], redB[4][4];
    float m[4] = {ej[0], ej[1], ej[2], ej[3]};
#pragma unroll
    for (int off = 32; off > 0; off >>= 1) {
#pragma unroll
        for (int ii = 0; ii < 4; ++ii) m[ii] = fmaxf(m[ii], __shfl_xor(m[ii], off));
    }
    int wv = tid >> 6;
    if ((tid & 63) == 0) {
#pragma unroll
        for (int ii = 0; ii < 4; ++ii) redA[wv][ii] = m[ii];
    }
    __syncthreads();
    float p[4], ps[4];
#pragma unroll
    for (int ii = 0; ii < 4; ++ii) {
        float mx = fmaxf(redA[wv][ii], redA[wv ^ 1][ii]);
        p[ii] = (j < WW) ? __expf(ej[ii] - mx) : 0.f;
        ps[ii] = p[ii];
    }
#pragma unroll
    for (int off = 32; off > 0; off >>= 1) {
#pragma unroll
        for (int ii = 0; ii < 4; ++ii) ps[ii] += __shfl_xor(ps[ii], off);
    }
    if ((tid & 63) == 0) {
#pragma unroll
        for (int ii = 0; ii < 4; ++ii) redB[wv][ii] = ps[ii];
    }
    __syncthreads();
    __shared__ float attT[WW][12];
    if (j < WW) {
#pragma unroll
        for (int ii = 0; ii < 4; ++ii) {
            float inv = 1.f / (redB[wv][ii] + redB[wv ^ 1][ii]);
            attT[j][q * 4 + ii] = p[ii] * inv;
        }
    }
    __syncthreads();
    // PV: threads = d(128) x ph(2); ph*4+ii indexes the 8 queries
    int d = tid & 127, ph = tid >> 7;
    float pv0 = 0.f, pv1 = 0.f, pv2 = 0.f, pv3 = 0.f;
    for (int jj = 0; jj < WW; ++jj) {
        float4 av = *(const float4*)&attT[jj][ph * 4];
        float xv = x2[(b * WW + jj) * FF + d];
        pv0 += av.x * xv; pv1 += av.y * xv; pv2 += av.z * xv; pv3 += av.w * xv;
    }
    __shared__ float ob[FF][12];
    ob[d][ph * 4 + 0] = tanhf(pv0);
    ob[d][ph * 4 + 1] = tanhf(pv1);
    ob[d][ph * 4 + 2] = tanhf(pv2);
    ob[d][ph * 4 + 3] = tanhf(pv3);
    __syncthreads();
    {
        int f = tid >> 1, h4 = (tid & 1) * 4;
        if (i0 + h4 < WW) {
            float4 v = *(const float4*)&ob[f][h4];
            *(float4*)&x3T[(b * FF + f) * WW + i0 + h4] = v;
        }
    }
}

// K4: feature L/R GEMM, 8 f-rows/block. LfT/RfT (B,200,128) transposed.
__global__ __launch_bounds__(256) void k_lr_f(const float* __restrict__ x3T,
                                              const float* __restrict__ flwT,
                                              const float* __restrict__ flb,
                                              float* __restrict__ LfT,
                                              float* __restrict__ RfT) {
    int tile = blockIdx.x & 15;
    int b = blockIdx.x >> 4;
    int f0 = tile * 8;
    int e = threadIdx.x;
    if (e >= EF) return;
    const float* xrow = x3T + (b * FF + f0) * WW;
    float aL[8] = {0,0,0,0,0,0,0,0}, aR[8] = {0,0,0,0,0,0,0,0};
    for (int dc = 0; dc < 25; ++dc) {
        float xs_[8][4];
#pragma unroll
        for (int r = 0; r < 8; ++r)
            *(float4*)xs_[r] = *(const float4*)&xrow[r * WW + dc * 4];  // uniform
#pragma unroll
        for (int q = 0; q < 4; ++q) {
            int d = dc * 4 + q;
            float wL = flwT[d * EF + e];
            float wR = flwT[(WW + d) * EF + e];
#pragma unroll
            for (int r = 0; r < 8; ++r) {
                aL[r] += xs_[r][q] * wL;
                aR[r] += xs_[r][q] * wR;
            }
        }
    }
    float lb = flb[e];
    float o0[8];
#pragma unroll
    for (int r = 0; r < 8; ++r) o0[r] = aL[r] + lb;
    float* Lp = LfT + (b * EF + e) * FF + f0;
    float* Rp = RfT + (b * EF + e) * FF + f0;
    *(float4*)Lp = *(float4*)&o0[0];
    *(float4*)(Lp + 4) = *(float4*)&o0[4];
    *(float4*)Rp = *(float4*)&aR[0];
    *(float4*)(Rp + 4) = *(float4*)&aR[4];
}

// K5: feature attention, QT=8 + fused tj reduction (x4 never materialized).
__global__ __launch_bounds__(256) void k_att_f(const float* __restrict__ LfT,
                                               const float* __restrict__ RfT,
                                               const float* __restrict__ fa,
                                               const float* __restrict__ fbias,
                                               const float* __restrict__ x3T,
                                               const float* __restrict__ fcw,
                                               float* __restrict__ tj) {
    int tile = blockIdx.x & 15;
    int b = blockIdx.x >> 4;
    int f0 = tile * 8;
    int tid = threadIdx.x;
    int j = tid & 127, q = tid >> 7;
    const float* Lb = LfT + (b * EF) * FF + f0 + q * 4;
    const float* Rb = RfT + (b * EF) * FF;
    float s0 = 0.f, s1 = 0.f, s2 = 0.f, s3 = 0.f;
    for (int e = 0; e < EF; ++e) {
        float rj = Rb[e * FF + j];
        float4 lv = *(const float4*)&Lb[e * FF];
        float ae = fa[e];
        float v;
        v = lv.x + rj; v = fmaxf(v, 0.2f * v); s0 += v * ae;
        v = lv.y + rj; v = fmaxf(v, 0.2f * v); s1 += v * ae;
        v = lv.z + rj; v = fmaxf(v, 0.2f * v); s2 += v * ae;
        v = lv.w + rj; v = fmaxf(v, 0.2f * v); s3 += v * ae;
    }
    float ej[4] = {s0, s1, s2, s3};
#pragma unroll
    for (int ii = 0; ii < 4; ++ii)
        ej[ii] += fbias[(f0 + q * 4 + ii) * FF + j];
    __shared__ float redA[4][4], redB[4][4];
    float m[4] = {ej[0], ej[1], ej[2], ej[3]};
#pragma unroll
    for (int off = 32; off > 0; off >>= 1) {
#pragma unroll
        for (int ii = 0; ii < 4; ++ii) m[ii] = fmaxf(m[ii], __shfl_xor(m[ii], off));
    }
    int wv = tid >> 6;
    if ((tid & 63) == 0) {
#pragma unroll
        for (int ii = 0; ii < 4; ++ii) redA[wv][ii] = m[ii];
    }
    __syncthreads();
    float p[4], ps[4];
#pragma unroll
    for (int ii = 0; ii < 4; ++ii) {
        float mx = fmaxf(redA[wv][ii], redA[wv ^ 1][ii]);
        p[ii] = __expf(ej[ii] - mx);
        ps[ii] = p[ii];
    }
#pragma unroll
    for (int off = 32; off > 0; off >>= 1) {
#pragma unroll
        for (int ii = 0; ii < 4; ++ii) ps[ii] += __shfl_xor(ps[ii], off);
    }
    if ((tid & 63) == 0) {
#pragma unroll
        for (int ii = 0; ii < 4; ++ii) redB[wv][ii] = ps[ii];
    }
    __syncthreads();
    __shared__ float attT[FF][12];
#pragma unroll
    for (int ii = 0; ii < 4; ++ii) {
        float inv = 1.f / (redB[wv][ii] + redB[wv ^ 1][ii]);
        attT[j][q * 4 + ii] = p[ii] * inv;
    }
    __syncthreads();
    // PV + tanh + fcw-weighted reduce over w
    int w = tid & 127, ph = tid >> 7;
    float pv[4] = {0.f, 0.f, 0.f, 0.f};
    float fcv = (w < WW) ? fcw[w] : 0.f;
    bool wok = (w < WW);
    for (int jj = 0; jj < FF; ++jj) {
        float4 av = *(const float4*)&attT[jj][ph * 4];
        float xv = wok ? x3T[(b * FF + jj) * WW + w] : 0.f;
        pv[0] += av.x * xv; pv[1] += av.y * xv;
        pv[2] += av.z * xv; pv[3] += av.w * xv;
    }
    float tv[4];
#pragma unroll
    for (int ii = 0; ii < 4; ++ii) tv[ii] = tanhf(pv[ii]) * fcv;
#pragma unroll
    for (int off = 32; off > 0; off >>= 1) {
#pragma unroll
        for (int ii = 0; ii < 4; ++ii) tv[ii] += __shfl_xor(tv[ii], off);
    }
    __shared__ float redT[4][4];
    if ((tid & 63) == 0) {
#pragma unroll
        for (int ii = 0; ii < 4; ++ii) redT[tid >> 6][ii] = tv[ii];
    }
    __syncthreads();
    if (tid < 8) {
        int hh = tid >> 2, ii = tid & 3;
        tj[b * FF + f0 + hh * 4 + ii] = redT[hh * 2][ii] + redT[hh * 2 + 1][ii];
    }
}

// K6: out[b,f] = tanh(sum_j cos(f,j)*tj[b,j] + fcb). cos from normalized emb.
__global__ __launch_bounds__(128) void k_fc(const float* __restrict__ tjg,
                                            const float* __restrict__ emb,
                                            const float* __restrict__ fcb,
                                            float* __restrict__ out) {
    int b = blockIdx.x;
    int f = threadIdx.x;
    __shared__ float en[FF][12];
    __shared__ float tjs[FF];
    {
        float4 e0 = *(const float4*)&emb[f * 8];
        float4 e1 = *(const float4*)&emb[f * 8 + 4];
        float n = e0.x*e0.x + e0.y*e0.y + e0.z*e0.z + e0.w*e0.w +
                  e1.x*e1.x + e1.y*e1.y + e1.z*e1.z + e1.w*e1.w;
        float rin = rsqrtf(n);
        float4 a = make_float4(e0.x*rin, e0.y*rin, e0.z*rin, e0.w*rin);
        float4 c = make_float4(e1.x*rin, e1.y*rin, e1.z*rin, e1.w*rin);
        *(float4*)&en[f][0] = a;
        *(float4*)&en[f][4] = c;
        tjs[f] = tjg[b * FF + f];
    }
    __syncthreads();
    float er[8];
#pragma unroll
    for (int k = 0; k < 8; ++k) er[k] = en[f][k];
    float acc = fcb[0];
    for (int jj = 0; jj < FF; ++jj) {
        float4 a = *(const float4*)&en[jj][0];
        float4 c = *(const float4*)&en[jj][4];
        float d8 = er[0]*a.x + er[1]*a.y + er[2]*a.z + er[3]*a.w +
                   er[4]*c.x + er[5]*c.y + er[6]*c.z + er[7]*c.w;
        acc += d8 * tjs[jj];
    }
    out[b * FF + f] = tanhf(acc);
}

extern "C" void kernel_launch(void* const* d_in, const int* in_sizes, int n_in,
                              void* d_out, int out_size, void* d_ws, size_t ws_size,
                              hipStream_t stream) {
    const float* x     = (const float*)d_in[0];
    const float* cw    = (const float*)d_in[1];
    const float* cb    = (const float*)d_in[2];
    const float* tlw   = (const float*)d_in[3];
    const float* tlb   = (const float*)d_in[4];
    const float* ta    = (const float*)d_in[5];
    const float* tbias = (const float*)d_in[6];
    const float* flw   = (const float*)d_in[7];
    const float* flb   = (const float*)d_in[8];
    const float* fa    = (const float*)d_in[9];
    const float* fbias = (const float*)d_in[10];
    const float* emb   = (const float*)d_in[11];
    const float* fcw   = (const float*)d_in[12];
    const float* fcb   = (const float*)d_in[13];
    float* out = (float*)d_out;
    float* ws = (float*)d_ws;

    float* x1   = ws + 0;
    float* x2   = ws + 409600;
    float* x3T  = ws + 819200;
    float* LT   = ws + 1228800;   // reused as LfT
    float* Rt   = ws + 2048000;   // reused as RfT
    float* tj   = ws + 2867200;
    float* wt   = ws + 3297280;
    float* tlwT = ws + 3411968;
    float* flwT = ws + 3477504;

    k_prep<<<1600, 256, 0, stream>>>(x, cw, tlw, flw, x1, wt, tlwT, flwT);
    k_conv<<<BB * NTILE, 256, 0, stream>>>(x1, wt, cb, x2);
    k_lr_t<<<BB * 13, 256, 0, stream>>>(x2, tlwT, tlb, LT, Rt);
    k_att_t<<<BB * 13, 256, 0, stream>>>(LT, Rt, ta, tbias, x2, x3T);
    k_lr_f<<<BB * 16, 256, 0, stream>>>(x3T, flwT, flb, LT, Rt);
    k_att_f<<<BB * 16, 256, 0, stream>>>(LT, Rt, fa, fbias, x3T, fcw, tj);
    k_fc<<<BB, 128, 0, stream>>>(tj, emb, fcb, out);
}